// Round 19
// baseline (56.116 us; speedup 1.0000x reference)
//
#include <hip/hip_runtime.h>
#include <hip/hip_bf16.h>
#include <stdint.h>

#define N_TOKENS    16384
#define MODEL_DIM   2048
#define NUM_EXPERTS 16
#define CAPACITY    2048
#define NBLK2       512    // 32-token half-chunks (== gemv blocks)
#define NBLK        256    // 64-token chunks for scatter
#define GBLK        512    // gemv blocks (32 tokens each)
// d_out is FLOAT32. [0]=l_aux, [1..32769)=weights[N][2],
// [32769..65537)=indices[E*CAP], [65537..98305)=expert_ids[E*CAP]
#define W_OFF       1
#define IDX_OFF     (1 + 2 * N_TOKENS)                  // 32769
#define EID_OFF     (IDX_OFF + NUM_EXPERTS * CAPACITY)  // 65537

// Scratch in d_ws. All regions fully (re)written by k_logits each call.
#define SC_E01    0        // uint8  [16384]: e1 | (e2<<4)
#define SC_CNTH   16384    // uint16 [16][512] routed counts per half-chunk
#define SC_CEH    32768    // uint16 [16][512] argmax counts per half-chunk
#define SC_ME     49152    // float  [512][16] gate sums per gemv block

// Cross-lane helpers. DPP quad_perm xor1=0xB1, xor2=0x4E; row_ror:8=0x128
// (== lane^8 within 16-lane rows). ds_swizzle BitMode: xor4=0x101F,
// xor16=0x401F (within 32-lane halves).
#define DPPX(v, ctrl) __int_as_float(__builtin_amdgcn_update_dpp(             \
    0, __float_as_int(v), (ctrl), 0xF, 0xF, true))
#define SWZ(v, off) __int_as_float(__builtin_amdgcn_ds_swizzle(               \
    __float_as_int(v), (off)))

// ============ K1: GEMV logits + softmax + top2 + weights + counts + me ======
// 512 blocks x 1024 thr (16 waves). 8-WAVES/SIMD WITHOUT x DUPLICATION
// (R17's flaw): split K not experts. Wave kr (0..15) owns k-range
// [kr*128,+128); lane slice = float2 (8B/lane, 512B/instr coalesced).
// w[16] = 16 float2 = 32 VGPR -> ~62 total -> natural <=64 budget, 7-8
// waves/SIMD, 2 blocks/CU, x read exactly ONCE (waves cover disjoint k).
// ROTATED layout (slot i = expert i^(l&15)) -> select-free folds, identical
// tree to R14: bits 0,1 DPP; bit 2 swizzle(xor4); bit 3 DPP row_ror:8;
// xor16 swizzle -> per-32-half partials. 2-deep x prefetch.
__global__ __launch_bounds__(1024) void k_logits(
    const float* __restrict__ x, const float* __restrict__ wg,
    float* __restrict__ out, uint8_t* __restrict__ ws)
{
  __shared__ float part[16][32][2][17];   // 69.6 KB -> 2 blocks/CU
  const int tid = threadIdx.x;
  const int b = blockIdx.x;
  const int l = tid & 63;
  const int kr = tid >> 6;             // 0..15
  const int kb = kr * 128 + l * 2;
  const int rot = l & 15;

  float2 w[16];
#pragma unroll
  for (int i = 0; i < NUM_EXPERTS; ++i)
    w[i] = *reinterpret_cast<const float2*>(wg + (size_t)((i ^ rot) * MODEL_DIM) + kb);

  const float* xp = x + (size_t)(b * 32) * MODEL_DIM + kb;
  float2 xva = *reinterpret_cast<const float2*>(xp);
  float2 xvb = *reinterpret_cast<const float2*>(xp + MODEL_DIM);

  for (int t = 0; t < 32; ++t) {
    float2 xvc;
    if (t < 30)
      xvc = *reinterpret_cast<const float2*>(xp + (size_t)(t + 2) * MODEL_DIM);

    float cur[16];
#pragma unroll
    for (int i = 0; i < NUM_EXPERTS; ++i)
      cur[i] = xva.x * w[i].x + xva.y * w[i].y;

    // select-free rotated folds: bit0 (DPP xor1)
#pragma unroll
    for (int r = 0; r < 8; ++r) cur[r] = cur[2 * r] + DPPX(cur[2 * r + 1], 0xB1);
    // bit1 (DPP xor2)
#pragma unroll
    for (int r = 0; r < 4; ++r) cur[r] = cur[2 * r] + DPPX(cur[2 * r + 1], 0x4E);
    // bit2 (ds_swizzle xor4)
#pragma unroll
    for (int r = 0; r < 2; ++r) cur[r] = cur[2 * r] + SWZ(cur[2 * r + 1], 0x101F);
    // bit3 (DPP row_ror:8 == xor8 within 16-lane rows)
    float v = cur[0] + DPPX(cur[1], 0x128);
    // 16-lane group sum (32 k-floats) -> 32-lane half sum (64 k-floats)
    v += SWZ(v, 0x401F);          // xor16 (within each 32-half)
    if ((l & 31) < 16) part[kr][t][l >> 5][l & 15] = v;
    xva = xvb; xvb = xvc;
  }
  __syncthreads();

  if (tid < 32) {   // lane = token within block
    const int tg = b * 32 + tid;
    float logit[NUM_EXPERTS];
#pragma unroll
    for (int e4 = 0; e4 < 4; ++e4) {
      float4 s = *reinterpret_cast<const float4*>(&part[0][tid][0][e4 * 4]);
#pragma unroll
      for (int k2 = 0; k2 < 16; ++k2) {
#pragma unroll
        for (int h = 0; h < 2; ++h) {
          if (k2 == 0 && h == 0) continue;
          float4 p = *reinterpret_cast<const float4*>(&part[k2][tid][h][e4 * 4]);
          s.x += p.x; s.y += p.y; s.z += p.z; s.w += p.w;
        }
      }
      logit[e4 * 4 + 0] = s.x; logit[e4 * 4 + 1] = s.y;
      logit[e4 * 4 + 2] = s.z; logit[e4 * 4 + 3] = s.w;
    }

    float m = logit[0];
#pragma unroll
    for (int e = 1; e < NUM_EXPERTS; e++) m = fmaxf(m, logit[e]);
    float gg[NUM_EXPERTS]; float z = 0.f;
#pragma unroll
    for (int e = 0; e < NUM_EXPERTS; e++) { gg[e] = expf(logit[e] - m); z += gg[e]; }
    float inv = 1.f / z;
#pragma unroll
    for (int e = 0; e < NUM_EXPERTS; e++) gg[e] *= inv;

    // top-2, ties -> lower index (matches lax.top_k / argmax)
    float v1 = gg[0], v2 = -1.f; int e1 = 0, e2 = 0;
#pragma unroll
    for (int e = 1; e < NUM_EXPERTS; e++) {
      if (gg[e] > v1) { v2 = v1; e2 = e1; v1 = gg[e]; e1 = e; }
      else if (gg[e] > v2) { v2 = gg[e]; e2 = e; }
    }
    out[W_OFF + 2 * tg]     = v1;
    out[W_OFF + 2 * tg + 1] = v2;
    ws[SC_E01 + tg] = (uint8_t)(e1 | (e2 << 4));

    // per-half-chunk routed counts + argmax counts (32 active lanes)
    int mycount = 0, myce = 0;
    for (int e = 0; e < NUM_EXPERTS; e++) {
      unsigned long long m1 = __ballot(e1 == e);
      unsigned long long m2 = __ballot(e2 == e);
      if (tid == e) { mycount = __popcll(m1 | m2); myce = __popcll(m1); }
    }
    if (tid < NUM_EXPERTS) {
      reinterpret_cast<uint16_t*>(ws + SC_CNTH)[tid * NBLK2 + b] = (uint16_t)mycount;
      reinterpret_cast<uint16_t*>(ws + SC_CEH)[tid * NBLK2 + b] = (uint16_t)myce;
    }

    // me partial over the block's 32 tokens
#pragma unroll
    for (int e = 0; e < NUM_EXPERTS; e++) {
      gg[e] += __shfl_xor(gg[e], 1, 64);
      gg[e] += __shfl_xor(gg[e], 2, 64);
      gg[e] += __shfl_xor(gg[e], 4, 64);
      gg[e] += __shfl_xor(gg[e], 8, 64);
      gg[e] += __shfl_xor(gg[e], 16, 64);
    }
    if (tid == 0) {
      float* mp = reinterpret_cast<float*>(ws + SC_ME);
#pragma unroll
      for (int e = 0; e < NUM_EXPERTS; e++) mp[b * NUM_EXPERTS + e] = gg[e];
    }
  }
}

// ============ K2: per-block prefix + scatter + fill + eid + l_aux ============
__global__ __launch_bounds__(192) void k_tail(
    const uint8_t* __restrict__ ws, float* __restrict__ out) {
  __shared__ int sstart[NUM_EXPERTS];
  __shared__ int stot[NUM_EXPERTS];
  const int tid = threadIdx.x;
  const int b = blockIdx.x;

  if (b == 256) {   // l_aux
    __shared__ float sme2[12][NUM_EXPERTS];
    __shared__ int sce2[12][NUM_EXPERTS];
    const float* me = reinterpret_cast<const float*>(ws + SC_ME);
    const uint16_t* ceh = reinterpret_cast<const uint16_t*>(ws + SC_CEH);
    const int e = tid & 15, grp = tid >> 4;   // 12 groups
    float ms = 0.f; int cs = 0;
    for (int k = grp; k < NBLK2; k += 12) {
      ms += me[k * NUM_EXPERTS + e];
      cs += ceh[e * NBLK2 + k];
    }
    sme2[grp][e] = ms; sce2[grp][e] = cs;
    __syncthreads();
    if (tid < NUM_EXPERTS) {
      float ssum = 0.f; int ce = 0;
#pragma unroll
      for (int g2 = 0; g2 < 12; g2++) { ssum += sme2[g2][tid]; ce += sce2[g2][tid]; }
      float prod = (ssum * (1.0f / N_TOKENS)) * ((float)ce * (1.0f / N_TOKENS));
      prod += __shfl_xor(prod, 1, 64);
      prod += __shfl_xor(prod, 2, 64);
      prod += __shfl_xor(prod, 4, 64);
      prod += __shfl_xor(prod, 8, 64);
      if (tid == 0) out[0] = prod * (float)NUM_EXPERTS;
    }
    return;
  }

  // ---- blocks 0..255 ----
  if (tid < 64) {   // per-block prefix: lane (e = tid>>2, q = tid&3), uint4
    const int e = tid >> 2, q = tid & 3;
    const uint4* row =
        reinterpret_cast<const uint4*>(ws + SC_CNTH) + e * (NBLK2 / 8) + q * 16;
    const int limit = 2 * b;          // even -> u16 pairs never split
    int s_lt = 0, s_all = 0;
    for (int wd = 0; wd < 16; ++wd) {
      uint4 v = row[wd];
      int p0 = (int)(v.x & 0xFFFF) + (int)(v.x >> 16);
      int p1 = (int)(v.y & 0xFFFF) + (int)(v.y >> 16);
      int p2 = (int)(v.z & 0xFFFF) + (int)(v.z >> 16);
      int p3 = (int)(v.w & 0xFFFF) + (int)(v.w >> 16);
      s_all += p0 + p1 + p2 + p3;
      const int base = q * 128 + wd * 8;   // count-index of v.x
      if (base + 0 < limit) s_lt += p0;
      if (base + 2 < limit) s_lt += p1;
      if (base + 4 < limit) s_lt += p2;
      if (base + 6 < limit) s_lt += p3;
    }
    s_lt += __shfl_xor(s_lt, 1, 64);  s_lt += __shfl_xor(s_lt, 2, 64);
    s_all += __shfl_xor(s_all, 1, 64); s_all += __shfl_xor(s_all, 2, 64);
    if (q == 0) { sstart[e] = s_lt; stot[e] = s_all; }
  }
  __syncthreads();

  if (tid < 64) {   // wave 0: ballot scatter (lane = token in chunk b)
    const int t = b * 64 + tid;
    const int v = ws[SC_E01 + t];
    const int e1 = v & 15, e2 = v >> 4;
    const unsigned long long below = (1ull << tid) - 1ull;
    int p1 = CAPACITY, p2 = CAPACITY;
    for (int e = 0; e < NUM_EXPERTS; e++) {
      unsigned long long m = __ballot(e1 == e) | __ballot(e2 == e);
      int r = __popcll(m & below);
      int sbase = sstart[e];
      if (e1 == e) p1 = sbase + r;
      if (e2 == e) p2 = sbase + r;
    }
    float tf = (float)t;   // exact in fp32
    if ((unsigned)p1 < (unsigned)CAPACITY) out[IDX_OFF + e1 * CAPACITY + p1] = tf;
    if ((unsigned)p2 < (unsigned)CAPACITY) out[IDX_OFF + e2 * CAPACITY + p2] = tf;
  } else {          // waves 1-2: fill -1 + expert_ids for 128 slots
    const int slot = b * 128 + (tid - 64);   // 0..32767
    const int e = slot >> 11;                // == b/16, uniform per block
    const int p = slot & (CAPACITY - 1);
    if (p >= stot[e]) out[IDX_OFF + slot] = -1.0f;
    out[EID_OFF + slot] = (float)e;
  }
}

extern "C" void kernel_launch(void* const* d_in, const int* in_sizes, int n_in,
                              void* d_out, int out_size, void* d_ws, size_t ws_size,
                              hipStream_t stream) {
  const float* x  = (const float*)d_in[0];
  const float* wg = (const float*)d_in[1];
  float* out = (float*)d_out;
  uint8_t* ws = (uint8_t*)d_ws;

  k_logits<<<GBLK, 1024, 0, stream>>>(x, wg, out, ws);
  k_tail<<<257, 192, 0, stream>>>(ws, out);
}

// Round 20
// 51.989 us; speedup vs baseline: 1.0794x; 1.0794x over previous
//
#include <hip/hip_runtime.h>
#include <hip/hip_bf16.h>
#include <stdint.h>

#define N_TOKENS    16384
#define MODEL_DIM   2048
#define NUM_EXPERTS 16
#define CAPACITY    2048
#define NBLK2       512    // 32-token half-chunks (== gemv blocks)
#define NBLK        256    // 64-token chunks for scatter
#define GBLK        512    // gemv blocks (32 tokens each)
// d_out is FLOAT32. [0]=l_aux, [1..32769)=weights[N][2],
// [32769..65537)=indices[E*CAP], [65537..98305)=expert_ids[E*CAP]
#define W_OFF       1
#define IDX_OFF     (1 + 2 * N_TOKENS)                  // 32769
#define EID_OFF     (IDX_OFF + NUM_EXPERTS * CAPACITY)  // 65537

// Scratch in d_ws. All regions fully (re)written by k_logits each call.
#define SC_E01    0        // uint8  [16384]: e1 | (e2<<4)
#define SC_CNTH   16384    // uint16 [16][512] routed counts per half-chunk
#define SC_CEH    32768    // uint16 [16][512] argmax counts per half-chunk
#define SC_ME     49152    // float  [512][16] gate sums per gemv block

// Cross-lane helpers. DPP quad_perm xor1=0xB1, xor2=0x4E; row_ror:8=0x128
// (== lane^8 within 16-lane rows). ds_swizzle BitMode: xor4=0x101F,
// xor16=0x401F (within 32-lane halves).
#define DPPX(v, ctrl) __int_as_float(__builtin_amdgcn_update_dpp(             \
    0, __float_as_int(v), (ctrl), 0xF, 0xF, true))
#define SWZ(v, off) __int_as_float(__builtin_amdgcn_ds_swizzle(               \
    __float_as_int(v), (off)))

// Direct HBM->LDS async copy, 16B/lane: dest = wave-uniform base + lane*16,
// src = per-lane global address. Completion tracked by vmcnt.
#define ASYNC16(gsrc, ldst)                                                   \
  __builtin_amdgcn_global_load_lds(                                           \
      (const __attribute__((address_space(1))) void*)(gsrc),                  \
      (__attribute__((address_space(3))) void*)(ldst), 16, 0, 0)

// ============ K1: GEMV logits + softmax + top2 + weights + counts + me ======
// R14 structure/arithmetic (best: 48.8us, absmax 0.0) with the x-load path
// replaced by a per-wave 5-slot LDS ring fed by global_load_lds: 4 loads
// permanently in flight per wave (vs 2-deep reg prefetch) -> HBM latency
// (~900cy) covered by 4-token slack + 3 co-resident waves. Wave-private
// rings -> NO barriers in the loop. 512 blocks x 512 thr (8 waves,
// 2 blocks/CU). Wave kr owns k-range [kr*256,+256); lane slice 4 floats;
// PERSISTENT w[16] in 64 VGPRs, ROTATED layout (slot i = expert i^(l&15))
// -> select-free folds: bits 0,1 DPP; bit 2 swizzle(xor4); bit 3 DPP
// row_ror:8; xor16 swizzle -> per-32-half partials.
__global__ __launch_bounds__(512) void k_logits(
    const float* __restrict__ x, const float* __restrict__ wg,
    float* __restrict__ out, uint8_t* __restrict__ ws)
{
  __shared__ float part[8][32][2][17];   // 34.8 KB
  __shared__ float ring[8][5][256];      // 40 KB -> total 74 KB, 2 blk/CU
  const int tid = threadIdx.x;
  const int b = blockIdx.x;
  const int l = tid & 63;
  const int kr = tid >> 6;             // 0..7
  const int kb = kr * 256 + l * 4;
  const int rot = l & 15;

  float4 w[16];
#pragma unroll
  for (int i = 0; i < NUM_EXPERTS; ++i)
    w[i] = *reinterpret_cast<const float4*>(wg + (size_t)((i ^ rot) * MODEL_DIM) + kb);

  const float* xp = x + (size_t)(b * 32) * MODEL_DIM + kb;

  // prologue: stage tokens 0..3 into slots 0..3 (4 in flight)
  ASYNC16(xp + (size_t)0 * MODEL_DIM, &ring[kr][0][0]);
  ASYNC16(xp + (size_t)1 * MODEL_DIM, &ring[kr][1][0]);
  ASYNC16(xp + (size_t)2 * MODEL_DIM, &ring[kr][2][0]);
  ASYNC16(xp + (size_t)3 * MODEL_DIM, &ring[kr][3][0]);

  // Body for token T: issue token (T+4)&31 into slot WS=(T+4)%5 (wrap-around
  // dummies for T>=28 keep vmcnt a uniform literal; their slots are never
  // re-read), wait oldest (vmcnt(4) -> token T's load done), consume slot RS.
#define TOK_BODY(T, RS, WS)                                                    \
  {                                                                            \
    ASYNC16(xp + (size_t)(((T) + 4) & 31) * MODEL_DIM, &ring[kr][(WS)][0]);    \
    asm volatile("s_waitcnt vmcnt(4)" ::: "memory");                           \
    float4 xva = *reinterpret_cast<const float4*>(&ring[kr][(RS)][l * 4]);     \
    float cur[16];                                                             \
    _Pragma("unroll")                                                          \
    for (int i = 0; i < NUM_EXPERTS; ++i)                                      \
      cur[i] = xva.x * w[i].x + xva.y * w[i].y + xva.z * w[i].z +              \
               xva.w * w[i].w;                                                 \
    _Pragma("unroll")                                                          \
    for (int r = 0; r < 8; ++r) cur[r] = cur[2 * r] + DPPX(cur[2 * r + 1], 0xB1); \
    _Pragma("unroll")                                                          \
    for (int r = 0; r < 4; ++r) cur[r] = cur[2 * r] + DPPX(cur[2 * r + 1], 0x4E); \
    _Pragma("unroll")                                                          \
    for (int r = 0; r < 2; ++r) cur[r] = cur[2 * r] + SWZ(cur[2 * r + 1], 0x101F); \
    float vv = cur[0] + DPPX(cur[1], 0x128);                                   \
    vv += SWZ(vv, 0x401F);                                                     \
    if ((l & 31) < 16) part[kr][(T)][l >> 5][l & 15] = vv;                     \
  }

#pragma unroll 1
  for (int u = 0; u < 6; ++u) {        // tokens 0..29 (slots compile-time)
    const int t0 = u * 5;
    TOK_BODY(t0 + 0, 0, 4)
    TOK_BODY(t0 + 1, 1, 0)
    TOK_BODY(t0 + 2, 2, 1)
    TOK_BODY(t0 + 3, 3, 2)
    TOK_BODY(t0 + 4, 4, 3)
  }
  TOK_BODY(30, 0, 4)
  TOK_BODY(31, 1, 0)
#undef TOK_BODY
  __syncthreads();

  if (tid < 32) {   // lane = token within block
    const int tg = b * 32 + tid;
    float logit[NUM_EXPERTS];
#pragma unroll
    for (int e4 = 0; e4 < 4; ++e4) {
      float4 s = *reinterpret_cast<const float4*>(&part[0][tid][0][e4 * 4]);
#pragma unroll
      for (int k2 = 0; k2 < 8; ++k2) {
#pragma unroll
        for (int h = 0; h < 2; ++h) {
          if (k2 == 0 && h == 0) continue;
          float4 p = *reinterpret_cast<const float4*>(&part[k2][tid][h][e4 * 4]);
          s.x += p.x; s.y += p.y; s.z += p.z; s.w += p.w;
        }
      }
      logit[e4 * 4 + 0] = s.x; logit[e4 * 4 + 1] = s.y;
      logit[e4 * 4 + 2] = s.z; logit[e4 * 4 + 3] = s.w;
    }

    float m = logit[0];
#pragma unroll
    for (int e = 1; e < NUM_EXPERTS; e++) m = fmaxf(m, logit[e]);
    float gg[NUM_EXPERTS]; float z = 0.f;
#pragma unroll
    for (int e = 0; e < NUM_EXPERTS; e++) { gg[e] = expf(logit[e] - m); z += gg[e]; }
    float inv = 1.f / z;
#pragma unroll
    for (int e = 0; e < NUM_EXPERTS; e++) gg[e] *= inv;

    // top-2, ties -> lower index (matches lax.top_k / argmax)
    float v1 = gg[0], v2 = -1.f; int e1 = 0, e2 = 0;
#pragma unroll
    for (int e = 1; e < NUM_EXPERTS; e++) {
      if (gg[e] > v1) { v2 = v1; e2 = e1; v1 = gg[e]; e1 = e; }
      else if (gg[e] > v2) { v2 = gg[e]; e2 = e; }
    }
    out[W_OFF + 2 * tg]     = v1;
    out[W_OFF + 2 * tg + 1] = v2;
    ws[SC_E01 + tg] = (uint8_t)(e1 | (e2 << 4));

    // per-half-chunk routed counts + argmax counts (32 active lanes)
    int mycount = 0, myce = 0;
    for (int e = 0; e < NUM_EXPERTS; e++) {
      unsigned long long m1 = __ballot(e1 == e);
      unsigned long long m2 = __ballot(e2 == e);
      if (tid == e) { mycount = __popcll(m1 | m2); myce = __popcll(m1); }
    }
    if (tid < NUM_EXPERTS) {
      reinterpret_cast<uint16_t*>(ws + SC_CNTH)[tid * NBLK2 + b] = (uint16_t)mycount;
      reinterpret_cast<uint16_t*>(ws + SC_CEH)[tid * NBLK2 + b] = (uint16_t)myce;
    }

    // me partial over the block's 32 tokens
#pragma unroll
    for (int e = 0; e < NUM_EXPERTS; e++) {
      gg[e] += __shfl_xor(gg[e], 1, 64);
      gg[e] += __shfl_xor(gg[e], 2, 64);
      gg[e] += __shfl_xor(gg[e], 4, 64);
      gg[e] += __shfl_xor(gg[e], 8, 64);
      gg[e] += __shfl_xor(gg[e], 16, 64);
    }
    if (tid == 0) {
      float* mp = reinterpret_cast<float*>(ws + SC_ME);
#pragma unroll
      for (int e = 0; e < NUM_EXPERTS; e++) mp[b * NUM_EXPERTS + e] = gg[e];
    }
  }
}

// ============ K2: per-block prefix + scatter + fill + eid + l_aux ============
__global__ __launch_bounds__(192) void k_tail(
    const uint8_t* __restrict__ ws, float* __restrict__ out) {
  __shared__ int sstart[NUM_EXPERTS];
  __shared__ int stot[NUM_EXPERTS];
  const int tid = threadIdx.x;
  const int b = blockIdx.x;

  if (b == 256) {   // l_aux
    __shared__ float sme2[12][NUM_EXPERTS];
    __shared__ int sce2[12][NUM_EXPERTS];
    const float* me = reinterpret_cast<const float*>(ws + SC_ME);
    const uint16_t* ceh = reinterpret_cast<const uint16_t*>(ws + SC_CEH);
    const int e = tid & 15, grp = tid >> 4;   // 12 groups
    float ms = 0.f; int cs = 0;
    for (int k = grp; k < NBLK2; k += 12) {
      ms += me[k * NUM_EXPERTS + e];
      cs += ceh[e * NBLK2 + k];
    }
    sme2[grp][e] = ms; sce2[grp][e] = cs;
    __syncthreads();
    if (tid < NUM_EXPERTS) {
      float ssum = 0.f; int ce = 0;
#pragma unroll
      for (int g2 = 0; g2 < 12; g2++) { ssum += sme2[g2][tid]; ce += sce2[g2][tid]; }
      float prod = (ssum * (1.0f / N_TOKENS)) * ((float)ce * (1.0f / N_TOKENS));
      prod += __shfl_xor(prod, 1, 64);
      prod += __shfl_xor(prod, 2, 64);
      prod += __shfl_xor(prod, 4, 64);
      prod += __shfl_xor(prod, 8, 64);
      if (tid == 0) out[0] = prod * (float)NUM_EXPERTS;
    }
    return;
  }

  // ---- blocks 0..255 ----
  if (tid < 64) {   // per-block prefix: lane (e = tid>>2, q = tid&3), uint4
    const int e = tid >> 2, q = tid & 3;
    const uint4* row =
        reinterpret_cast<const uint4*>(ws + SC_CNTH) + e * (NBLK2 / 8) + q * 16;
    const int limit = 2 * b;          // even -> u16 pairs never split
    int s_lt = 0, s_all = 0;
    for (int wd = 0; wd < 16; ++wd) {
      uint4 v = row[wd];
      int p0 = (int)(v.x & 0xFFFF) + (int)(v.x >> 16);
      int p1 = (int)(v.y & 0xFFFF) + (int)(v.y >> 16);
      int p2 = (int)(v.z & 0xFFFF) + (int)(v.z >> 16);
      int p3 = (int)(v.w & 0xFFFF) + (int)(v.w >> 16);
      s_all += p0 + p1 + p2 + p3;
      const int base = q * 128 + wd * 8;   // count-index of v.x
      if (base + 0 < limit) s_lt += p0;
      if (base + 2 < limit) s_lt += p1;
      if (base + 4 < limit) s_lt += p2;
      if (base + 6 < limit) s_lt += p3;
    }
    s_lt += __shfl_xor(s_lt, 1, 64);  s_lt += __shfl_xor(s_lt, 2, 64);
    s_all += __shfl_xor(s_all, 1, 64); s_all += __shfl_xor(s_all, 2, 64);
    if (q == 0) { sstart[e] = s_lt; stot[e] = s_all; }
  }
  __syncthreads();

  if (tid < 64) {   // wave 0: ballot scatter (lane = token in chunk b)
    const int t = b * 64 + tid;
    const int v = ws[SC_E01 + t];
    const int e1 = v & 15, e2 = v >> 4;
    const unsigned long long below = (1ull << tid) - 1ull;
    int p1 = CAPACITY, p2 = CAPACITY;
    for (int e = 0; e < NUM_EXPERTS; e++) {
      unsigned long long m = __ballot(e1 == e) | __ballot(e2 == e);
      int r = __popcll(m & below);
      int sbase = sstart[e];
      if (e1 == e) p1 = sbase + r;
      if (e2 == e) p2 = sbase + r;
    }
    float tf = (float)t;   // exact in fp32
    if ((unsigned)p1 < (unsigned)CAPACITY) out[IDX_OFF + e1 * CAPACITY + p1] = tf;
    if ((unsigned)p2 < (unsigned)CAPACITY) out[IDX_OFF + e2 * CAPACITY + p2] = tf;
  } else {          // waves 1-2: fill -1 + expert_ids for 128 slots
    const int slot = b * 128 + (tid - 64);   // 0..32767
    const int e = slot >> 11;                // == b/16, uniform per block
    const int p = slot & (CAPACITY - 1);
    if (p >= stot[e]) out[IDX_OFF + slot] = -1.0f;
    out[EID_OFF + slot] = (float)e;
  }
}

extern "C" void kernel_launch(void* const* d_in, const int* in_sizes, int n_in,
                              void* d_out, int out_size, void* d_ws, size_t ws_size,
                              hipStream_t stream) {
  const float* x  = (const float*)d_in[0];
  const float* wg = (const float*)d_in[1];
  float* out = (float*)d_out;
  uint8_t* ws = (uint8_t*)d_ws;

  k_logits<<<GBLK, 512, 0, stream>>>(x, wg, out, ws);
  k_tail<<<257, 192, 0, stream>>>(ws, out);
}

// Round 21
// 49.018 us; speedup vs baseline: 1.1448x; 1.0606x over previous
//
#include <hip/hip_runtime.h>
#include <hip/hip_bf16.h>
#include <stdint.h>

#define N_TOKENS    16384
#define MODEL_DIM   2048
#define NUM_EXPERTS 16
#define CAPACITY    2048
#define NBLK2       512    // 32-token half-chunks (== gemv blocks)
#define NBLK        256    // 64-token chunks for scatter
#define GBLK        512    // gemv blocks (32 tokens each)
// d_out is FLOAT32. [0]=l_aux, [1..32769)=weights[N][2],
// [32769..65537)=indices[E*CAP], [65537..98305)=expert_ids[E*CAP]
#define W_OFF       1
#define IDX_OFF     (1 + 2 * N_TOKENS)                  // 32769
#define EID_OFF     (IDX_OFF + NUM_EXPERTS * CAPACITY)  // 65537

// Scratch in d_ws. All regions fully (re)written by k_logits each call.
#define SC_E01    0        // uint8  [16384]: e1 | (e2<<4)
#define SC_CNTH   16384    // uint16 [16][512] routed counts per half-chunk
#define SC_CEH    32768    // uint16 [16][512] argmax counts per half-chunk
#define SC_ME     49152    // float  [512][16] gate sums per gemv block

// Cross-lane helpers. DPP quad_perm xor1=0xB1, xor2=0x4E; row_ror:8=0x128
// (== lane^8 within 16-lane rows). ds_swizzle BitMode: xor4=0x101F,
// xor16=0x401F (within 32-lane halves).
#define DPPX(v, ctrl) __int_as_float(__builtin_amdgcn_update_dpp(             \
    0, __float_as_int(v), (ctrl), 0xF, 0xF, true))
#define SWZ(v, off) __int_as_float(__builtin_amdgcn_ds_swizzle(               \
    __float_as_int(v), (off)))

// ============ K1: GEMV logits + softmax + top2 + weights + counts + me ======
// R14 k_logits VERBATIM -- series best (48.8us total, absmax 0.0).
// 512 blocks x 512 thr (8 waves, 2 blocks/CU, 4 waves/SIMD). Wave kr owns
// k-range [kr*256,+256); lane slice 4 floats; PERSISTENT w[16] in 64 VGPRs,
// ROTATED layout (slot i = expert i^(l&15)) -> select-free folds; 2-deep x
// prefetch. Folds: bit0/bit1 DPP, bit2 swizzle(xor4), bit3 DPP row_ror:8,
// xor16 swizzle -> per-32-half partials. Per-kernel limit is the contended
// HBM x-stream (134 MB vs the harness's 512MB inter-replay d_ws fill).
__global__ __launch_bounds__(512) void k_logits(
    const float* __restrict__ x, const float* __restrict__ wg,
    float* __restrict__ out, uint8_t* __restrict__ ws)
{
  __shared__ float part[8][32][2][17];   // 34.8 KB
  const int tid = threadIdx.x;
  const int b = blockIdx.x;
  const int l = tid & 63;
  const int kr = tid >> 6;             // 0..7
  const int kb = kr * 256 + l * 4;
  const int rot = l & 15;

  float4 w[16];
#pragma unroll
  for (int i = 0; i < NUM_EXPERTS; ++i)
    w[i] = *reinterpret_cast<const float4*>(wg + (size_t)((i ^ rot) * MODEL_DIM) + kb);

  const float* xp = x + (size_t)(b * 32) * MODEL_DIM + kb;
  float4 xva = *reinterpret_cast<const float4*>(xp);
  float4 xvb = *reinterpret_cast<const float4*>(xp + MODEL_DIM);

#pragma unroll 2
  for (int t = 0; t < 32; ++t) {
    float4 xvc;
    if (t < 30)
      xvc = *reinterpret_cast<const float4*>(xp + (size_t)(t + 2) * MODEL_DIM);

    float cur[16];
#pragma unroll
    for (int i = 0; i < NUM_EXPERTS; ++i)
      cur[i] = xva.x * w[i].x + xva.y * w[i].y + xva.z * w[i].z + xva.w * w[i].w;

    // select-free rotated folds: bit0 (DPP xor1)
#pragma unroll
    for (int r = 0; r < 8; ++r) cur[r] = cur[2 * r] + DPPX(cur[2 * r + 1], 0xB1);
    // bit1 (DPP xor2)
#pragma unroll
    for (int r = 0; r < 4; ++r) cur[r] = cur[2 * r] + DPPX(cur[2 * r + 1], 0x4E);
    // bit2 (ds_swizzle xor4)
#pragma unroll
    for (int r = 0; r < 2; ++r) cur[r] = cur[2 * r] + SWZ(cur[2 * r + 1], 0x101F);
    // bit3 (DPP row_ror:8 == xor8 within 16-lane rows)
    float v = cur[0] + DPPX(cur[1], 0x128);
    // 16-lane group sum -> 32-lane half sum
    v += SWZ(v, 0x401F);          // xor16 (within each 32-half)
    if ((l & 31) < 16) part[kr][t][l >> 5][l & 15] = v;
    xva = xvb; xvb = xvc;
  }
  __syncthreads();

  if (tid < 32) {   // lane = token within block
    const int tg = b * 32 + tid;
    float logit[NUM_EXPERTS];
#pragma unroll
    for (int e4 = 0; e4 < 4; ++e4) {
      float4 s = *reinterpret_cast<const float4*>(&part[0][tid][0][e4 * 4]);
#pragma unroll
      for (int k2 = 0; k2 < 8; ++k2) {
#pragma unroll
        for (int h = 0; h < 2; ++h) {
          if (k2 == 0 && h == 0) continue;
          float4 p = *reinterpret_cast<const float4*>(&part[k2][tid][h][e4 * 4]);
          s.x += p.x; s.y += p.y; s.z += p.z; s.w += p.w;
        }
      }
      logit[e4 * 4 + 0] = s.x; logit[e4 * 4 + 1] = s.y;
      logit[e4 * 4 + 2] = s.z; logit[e4 * 4 + 3] = s.w;
    }

    float m = logit[0];
#pragma unroll
    for (int e = 1; e < NUM_EXPERTS; e++) m = fmaxf(m, logit[e]);
    float gg[NUM_EXPERTS]; float z = 0.f;
#pragma unroll
    for (int e = 0; e < NUM_EXPERTS; e++) { gg[e] = expf(logit[e] - m); z += gg[e]; }
    float inv = 1.f / z;
#pragma unroll
    for (int e = 0; e < NUM_EXPERTS; e++) gg[e] *= inv;

    // top-2, ties -> lower index (matches lax.top_k / argmax)
    float v1 = gg[0], v2 = -1.f; int e1 = 0, e2 = 0;
#pragma unroll
    for (int e = 1; e < NUM_EXPERTS; e++) {
      if (gg[e] > v1) { v2 = v1; e2 = e1; v1 = gg[e]; e1 = e; }
      else if (gg[e] > v2) { v2 = gg[e]; e2 = e; }
    }
    out[W_OFF + 2 * tg]     = v1;
    out[W_OFF + 2 * tg + 1] = v2;
    ws[SC_E01 + tg] = (uint8_t)(e1 | (e2 << 4));

    // per-half-chunk routed counts + argmax counts (32 active lanes)
    int mycount = 0, myce = 0;
    for (int e = 0; e < NUM_EXPERTS; e++) {
      unsigned long long m1 = __ballot(e1 == e);
      unsigned long long m2 = __ballot(e2 == e);
      if (tid == e) { mycount = __popcll(m1 | m2); myce = __popcll(m1); }
    }
    if (tid < NUM_EXPERTS) {
      reinterpret_cast<uint16_t*>(ws + SC_CNTH)[tid * NBLK2 + b] = (uint16_t)mycount;
      reinterpret_cast<uint16_t*>(ws + SC_CEH)[tid * NBLK2 + b] = (uint16_t)myce;
    }

    // me partial over the block's 32 tokens
#pragma unroll
    for (int e = 0; e < NUM_EXPERTS; e++) {
      gg[e] += __shfl_xor(gg[e], 1, 64);
      gg[e] += __shfl_xor(gg[e], 2, 64);
      gg[e] += __shfl_xor(gg[e], 4, 64);
      gg[e] += __shfl_xor(gg[e], 8, 64);
      gg[e] += __shfl_xor(gg[e], 16, 64);
    }
    if (tid == 0) {
      float* mp = reinterpret_cast<float*>(ws + SC_ME);
#pragma unroll
      for (int e = 0; e < NUM_EXPERTS; e++) mp[b * NUM_EXPERTS + e] = gg[e];
    }
  }
}

// ============ K2: per-block prefix + scatter + fill + eid + l_aux ============
// uint4 prefix loads (R18's tail -- 4x fewer serial L2 round-trips).
__global__ __launch_bounds__(192) void k_tail(
    const uint8_t* __restrict__ ws, float* __restrict__ out) {
  __shared__ int sstart[NUM_EXPERTS];
  __shared__ int stot[NUM_EXPERTS];
  const int tid = threadIdx.x;
  const int b = blockIdx.x;

  if (b == 256) {   // l_aux
    __shared__ float sme2[12][NUM_EXPERTS];
    __shared__ int sce2[12][NUM_EXPERTS];
    const float* me = reinterpret_cast<const float*>(ws + SC_ME);
    const uint16_t* ceh = reinterpret_cast<const uint16_t*>(ws + SC_CEH);
    const int e = tid & 15, grp = tid >> 4;   // 12 groups
    float ms = 0.f; int cs = 0;
    for (int k = grp; k < NBLK2; k += 12) {
      ms += me[k * NUM_EXPERTS + e];
      cs += ceh[e * NBLK2 + k];
    }
    sme2[grp][e] = ms; sce2[grp][e] = cs;
    __syncthreads();
    if (tid < NUM_EXPERTS) {
      float ssum = 0.f; int ce = 0;
#pragma unroll
      for (int g2 = 0; g2 < 12; g2++) { ssum += sme2[g2][tid]; ce += sce2[g2][tid]; }
      float prod = (ssum * (1.0f / N_TOKENS)) * ((float)ce * (1.0f / N_TOKENS));
      prod += __shfl_xor(prod, 1, 64);
      prod += __shfl_xor(prod, 2, 64);
      prod += __shfl_xor(prod, 4, 64);
      prod += __shfl_xor(prod, 8, 64);
      if (tid == 0) out[0] = prod * (float)NUM_EXPERTS;
    }
    return;
  }

  // ---- blocks 0..255 ----
  if (tid < 64) {   // per-block prefix: lane (e = tid>>2, q = tid&3), uint4
    const int e = tid >> 2, q = tid & 3;
    const uint4* row =
        reinterpret_cast<const uint4*>(ws + SC_CNTH) + e * (NBLK2 / 8) + q * 16;
    const int limit = 2 * b;          // even -> u16 pairs never split
    int s_lt = 0, s_all = 0;
    for (int wd = 0; wd < 16; ++wd) {
      uint4 v = row[wd];
      int p0 = (int)(v.x & 0xFFFF) + (int)(v.x >> 16);
      int p1 = (int)(v.y & 0xFFFF) + (int)(v.y >> 16);
      int p2 = (int)(v.z & 0xFFFF) + (int)(v.z >> 16);
      int p3 = (int)(v.w & 0xFFFF) + (int)(v.w >> 16);
      s_all += p0 + p1 + p2 + p3;
      const int base = q * 128 + wd * 8;   // count-index of v.x
      if (base + 0 < limit) s_lt += p0;
      if (base + 2 < limit) s_lt += p1;
      if (base + 4 < limit) s_lt += p2;
      if (base + 6 < limit) s_lt += p3;
    }
    s_lt += __shfl_xor(s_lt, 1, 64);  s_lt += __shfl_xor(s_lt, 2, 64);
    s_all += __shfl_xor(s_all, 1, 64); s_all += __shfl_xor(s_all, 2, 64);
    if (q == 0) { sstart[e] = s_lt; stot[e] = s_all; }
  }
  __syncthreads();

  if (tid < 64) {   // wave 0: ballot scatter (lane = token in chunk b)
    const int t = b * 64 + tid;
    const int v = ws[SC_E01 + t];
    const int e1 = v & 15, e2 = v >> 4;
    const unsigned long long below = (1ull << tid) - 1ull;
    int p1 = CAPACITY, p2 = CAPACITY;
    for (int e = 0; e < NUM_EXPERTS; e++) {
      unsigned long long m = __ballot(e1 == e) | __ballot(e2 == e);
      int r = __popcll(m & below);
      int sbase = sstart[e];
      if (e1 == e) p1 = sbase + r;
      if (e2 == e) p2 = sbase + r;
    }
    float tf = (float)t;   // exact in fp32
    if ((unsigned)p1 < (unsigned)CAPACITY) out[IDX_OFF + e1 * CAPACITY + p1] = tf;
    if ((unsigned)p2 < (unsigned)CAPACITY) out[IDX_OFF + e2 * CAPACITY + p2] = tf;
  } else {          // waves 1-2: fill -1 + expert_ids for 128 slots
    const int slot = b * 128 + (tid - 64);   // 0..32767
    const int e = slot >> 11;                // == b/16, uniform per block
    const int p = slot & (CAPACITY - 1);
    if (p >= stot[e]) out[IDX_OFF + slot] = -1.0f;
    out[EID_OFF + slot] = (float)e;
  }
}

extern "C" void kernel_launch(void* const* d_in, const int* in_sizes, int n_in,
                              void* d_out, int out_size, void* d_ws, size_t ws_size,
                              hipStream_t stream) {
  const float* x  = (const float*)d_in[0];
  const float* wg = (const float*)d_in[1];
  float* out = (float*)d_out;
  uint8_t* ws = (uint8_t*)d_ws;

  k_logits<<<GBLK, 512, 0, stream>>>(x, wg, out, ws);
  k_tail<<<257, 192, 0, stream>>>(ws, out);
}